// Round 1
// baseline (1282.788 us; speedup 1.0000x reference)
//
#include <hip/hip_runtime.h>

#define S_LEN 2048
#define DM    512
#define NH    8
#define HD    64

// ============================================================
// Fused QKV projection:  out[e] = sum_d x[m,d] * W[e,d] + b[e]
// Writes Q/K/V in [B, H, S, HD] layout (head-major for attention).
// grid = (M/64, 24): y>>3 selects Q/K/V, y&7 selects head (64-col block).
// 64x64 C-tile, BK=32, 4x4 microtile, LDS transposed (k-major).
// ============================================================
__global__ __launch_bounds__(256) void qkv_proj(
    const float* __restrict__ x,
    const float* __restrict__ Wq, const float* __restrict__ bq,
    const float* __restrict__ Wk, const float* __restrict__ bk,
    const float* __restrict__ Wv, const float* __restrict__ bv,
    float* __restrict__ Q, float* __restrict__ K, float* __restrict__ V)
{
    __shared__ float As[32][68];
    __shared__ float Bs[32][68];

    const int t  = threadIdx.x;
    const int which = blockIdx.y >> 3;     // 0=Q 1=K 2=V
    const int nb = blockIdx.y & 7;         // head block
    const int m0 = blockIdx.x * 64;
    const int n0 = nb * 64;

    const float* __restrict__ W    = (which == 0) ? Wq : (which == 1) ? Wk : Wv;
    const float* __restrict__ bias = (which == 0) ? bq : (which == 1) ? bk : bv;
    float* __restrict__ out        = (which == 0) ? Q  : (which == 1) ? K  : V;

    const int tx = t & 15, ty = t >> 4;
    const int lr = t >> 2;          // load row 0..63
    const int lk = (t & 3) * 4;     // load k offset {0,4,8,12}, +16 for 2nd

    float acc[4][4] = {};
    for (int k0 = 0; k0 < DM; k0 += 32) {
        float4 a0 = *(const float4*)&x[(size_t)(m0 + lr) * DM + k0 + lk];
        float4 a1 = *(const float4*)&x[(size_t)(m0 + lr) * DM + k0 + lk + 16];
        float4 b0 = *(const float4*)&W[(size_t)(n0 + lr) * DM + k0 + lk];
        float4 b1 = *(const float4*)&W[(size_t)(n0 + lr) * DM + k0 + lk + 16];
        __syncthreads();
        As[lk+0][lr]=a0.x; As[lk+1][lr]=a0.y; As[lk+2][lr]=a0.z; As[lk+3][lr]=a0.w;
        As[lk+16][lr]=a1.x; As[lk+17][lr]=a1.y; As[lk+18][lr]=a1.z; As[lk+19][lr]=a1.w;
        Bs[lk+0][lr]=b0.x; Bs[lk+1][lr]=b0.y; Bs[lk+2][lr]=b0.z; Bs[lk+3][lr]=b0.w;
        Bs[lk+16][lr]=b1.x; Bs[lk+17][lr]=b1.y; Bs[lk+18][lr]=b1.z; Bs[lk+19][lr]=b1.w;
        __syncthreads();
        #pragma unroll
        for (int kk = 0; kk < 32; ++kk) {
            float4 av = *(const float4*)&As[kk][ty * 4];
            float4 bv4 = *(const float4*)&Bs[kk][tx * 4];
            float a[4] = {av.x, av.y, av.z, av.w};
            float b[4] = {bv4.x, bv4.y, bv4.z, bv4.w};
            #pragma unroll
            for (int i = 0; i < 4; ++i)
                #pragma unroll
                for (int j = 0; j < 4; ++j)
                    acc[i][j] = fmaf(a[i], b[j], acc[i][j]);
        }
    }

    const int b  = m0 >> 11;                 // m0 / 2048 (tile never straddles batch)
    const int s0 = (m0 & 2047) + ty * 4;
    float bj[4];
    #pragma unroll
    for (int j = 0; j < 4; ++j) bj[j] = bias[n0 + tx * 4 + j];
    #pragma unroll
    for (int i = 0; i < 4; ++i) {
        float4 c;
        c.x = acc[i][0] + bj[0];
        c.y = acc[i][1] + bj[1];
        c.z = acc[i][2] + bj[2];
        c.w = acc[i][3] + bj[3];
        *(float4*)&out[((size_t)(b * NH + nb) * S_LEN + s0 + i) * HD + tx * 4] = c;
    }
}

// ============================================================
// Flash attention (fp32, online softmax), causal.
// grid = (S/64, B*H). One block = 64-query tile for one (b,h).
// K tile and V tile share one LDS buffer (loaded sequentially).
// ============================================================
__global__ __launch_bounds__(256) void attn(
    const float* __restrict__ Q, const float* __restrict__ K,
    const float* __restrict__ V, float* __restrict__ Att)
{
    __shared__ float Qs[HD][68];     // [d][row]  (transposed)
    __shared__ float KV[HD][68];     // K phase: [d][col]; V phase: [j][d]
    __shared__ float Pt[64][68];     // [col][row]
    __shared__ float red[4][64];
    __shared__ float row_m[64], row_l[64], row_al[64];

    const int t  = threadIdx.x;
    const int bh = blockIdx.y;
    const int qt = blockIdx.x;
    const int q0 = qt * 64;
    const size_t base = (size_t)bh * S_LEN * HD;

    const int tx = t & 15, ty = t >> 4;
    const int lr = t >> 2;           // load row 0..63
    const int lc = (t & 3) * 16;     // load col offset

    float* KVf = &KV[0][0];

    // load + transpose Q tile
    {
        const float* src = Q + base + (size_t)q0 * HD;
        #pragma unroll
        for (int u = 0; u < 4; ++u) {
            float4 v = *(const float4*)&src[lr * HD + lc + u * 4];
            Qs[lc + u*4 + 0][lr] = v.x;
            Qs[lc + u*4 + 1][lr] = v.y;
            Qs[lc + u*4 + 2][lr] = v.z;
            Qs[lc + u*4 + 3][lr] = v.w;
        }
    }
    if (t < 64) { row_m[t] = -1e30f; row_l[t] = 0.0f; }
    float o[4][4] = {};
    __syncthreads();

    for (int kt = 0; kt <= qt; ++kt) {
        // ---- load K tile (transposed) ----
        {
            const float* ksrc = K + base + (size_t)kt * 64 * HD;
            #pragma unroll
            for (int u = 0; u < 4; ++u) {
                float4 v = *(const float4*)&ksrc[lr * HD + lc + u * 4];
                KV[lc + u*4 + 0][lr] = v.x;
                KV[lc + u*4 + 1][lr] = v.y;
                KV[lc + u*4 + 2][lr] = v.z;
                KV[lc + u*4 + 3][lr] = v.w;
            }
        }
        __syncthreads();

        // ---- S = Q K^T (4x4 per thread) ----
        float s[4][4] = {};
        #pragma unroll 8
        for (int d = 0; d < HD; ++d) {
            float4 av = *(const float4*)&Qs[d][ty * 4];
            float4 bv4 = *(const float4*)&KV[d][tx * 4];
            float a[4] = {av.x, av.y, av.z, av.w};
            float b[4] = {bv4.x, bv4.y, bv4.z, bv4.w};
            #pragma unroll
            for (int i = 0; i < 4; ++i)
                #pragma unroll
                for (int j = 0; j < 4; ++j)
                    s[i][j] = fmaf(a[i], b[j], s[i][j]);
        }
        __syncthreads();   // K reads done; KV reusable for V

        // ---- scale + causal mask + store Pt; load V into KV ----
        #pragma unroll
        for (int i = 0; i < 4; ++i)
            #pragma unroll
            for (int j = 0; j < 4; ++j) {
                float sv = s[i][j] * 0.125f;
                if (kt == qt && (tx * 4 + j) > (ty * 4 + i)) sv = -1e30f;
                Pt[tx * 4 + j][ty * 4 + i] = sv;
            }
        {
            const float* vsrc = V + base + (size_t)kt * 64 * HD;
            #pragma unroll
            for (int u = 0; u < 4; ++u) {
                float4 v = *(const float4*)&vsrc[lr * HD + lc + u * 4];
                *(float4*)&KVf[lr * 68 + lc + u * 4] = v;
            }
        }
        __syncthreads();

        // ---- softmax phase A: partial row max ----
        {
            const int rr = t & 63, part = t >> 6;
            float m = -1e30f;
            for (int j = part * 16; j < part * 16 + 16; ++j)
                m = fmaxf(m, Pt[j][rr]);
            red[part][rr] = m;
        }
        __syncthreads();
        // ---- phase B: combine max, alpha ----
        if (t < 64) {
            float m_new = fmaxf(fmaxf(red[0][t], red[1][t]),
                                fmaxf(red[2][t], red[3][t]));
            m_new = fmaxf(m_new, row_m[t]);
            float al = __expf(row_m[t] - m_new);
            row_al[t] = al;
            row_m[t]  = m_new;
            row_l[t] *= al;
        }
        __syncthreads();
        // ---- phase C: exp + partial sums ----
        {
            const int rr = t & 63, part = t >> 6;
            const float mrow = row_m[rr];
            float sum = 0.0f;
            for (int j = part * 16; j < part * 16 + 16; ++j) {
                float p = __expf(Pt[j][rr] - mrow);
                Pt[j][rr] = p;
                sum += p;
            }
            red[part][rr] = sum;
        }
        __syncthreads();
        if (t < 64)
            row_l[t] += red[0][t] + red[1][t] + red[2][t] + red[3][t];

        // ---- rescale O, accumulate P·V ----
        {
            float al[4];
            #pragma unroll
            for (int i = 0; i < 4; ++i) al[i] = row_al[ty * 4 + i];
            #pragma unroll
            for (int i = 0; i < 4; ++i)
                #pragma unroll
                for (int j = 0; j < 4; ++j) o[i][j] *= al[i];
            #pragma unroll 8
            for (int j = 0; j < 64; ++j) {
                float4 pv = *(const float4*)&Pt[j][ty * 4];
                float4 vv = *(const float4*)&KVf[j * 68 + tx * 4];
                float p[4] = {pv.x, pv.y, pv.z, pv.w};
                float v[4] = {vv.x, vv.y, vv.z, vv.w};
                #pragma unroll
                for (int i = 0; i < 4; ++i)
                    #pragma unroll
                    for (int jj = 0; jj < 4; ++jj)
                        o[i][jj] = fmaf(p[i], v[jj], o[i][jj]);
            }
        }
        __syncthreads();   // protect KV/Pt for next iteration (and row_l for epilogue)
    }

    // ---- epilogue: normalize, write attended [B*S, DM] ----
    const int b = bh >> 3, h = bh & 7;
    #pragma unroll
    for (int i = 0; i < 4; ++i) {
        float inv = 1.0f / row_l[ty * 4 + i];
        float4 c;
        c.x = o[i][0] * inv;
        c.y = o[i][1] * inv;
        c.z = o[i][2] * inv;
        c.w = o[i][3] * inv;
        *(float4*)&Att[(size_t)(b * S_LEN + q0 + ty * 4 + i) * DM + h * HD + tx * 4] = c;
    }
}

// ============================================================
// Output projection: out = A @ Wo^T + bo   (A: [8192, 512])
// ============================================================
__global__ __launch_bounds__(256) void out_proj(
    const float* __restrict__ A,
    const float* __restrict__ Wo, const float* __restrict__ bo,
    float* __restrict__ out)
{
    __shared__ float As[32][68];
    __shared__ float Bs[32][68];

    const int t  = threadIdx.x;
    const int m0 = blockIdx.x * 64;
    const int n0 = blockIdx.y * 64;

    const int tx = t & 15, ty = t >> 4;
    const int lr = t >> 2;
    const int lk = (t & 3) * 4;

    float acc[4][4] = {};
    for (int k0 = 0; k0 < DM; k0 += 32) {
        float4 a0 = *(const float4*)&A [(size_t)(m0 + lr) * DM + k0 + lk];
        float4 a1 = *(const float4*)&A [(size_t)(m0 + lr) * DM + k0 + lk + 16];
        float4 b0 = *(const float4*)&Wo[(size_t)(n0 + lr) * DM + k0 + lk];
        float4 b1 = *(const float4*)&Wo[(size_t)(n0 + lr) * DM + k0 + lk + 16];
        __syncthreads();
        As[lk+0][lr]=a0.x; As[lk+1][lr]=a0.y; As[lk+2][lr]=a0.z; As[lk+3][lr]=a0.w;
        As[lk+16][lr]=a1.x; As[lk+17][lr]=a1.y; As[lk+18][lr]=a1.z; As[lk+19][lr]=a1.w;
        Bs[lk+0][lr]=b0.x; Bs[lk+1][lr]=b0.y; Bs[lk+2][lr]=b0.z; Bs[lk+3][lr]=b0.w;
        Bs[lk+16][lr]=b1.x; Bs[lk+17][lr]=b1.y; Bs[lk+18][lr]=b1.z; Bs[lk+19][lr]=b1.w;
        __syncthreads();
        #pragma unroll
        for (int kk = 0; kk < 32; ++kk) {
            float4 av = *(const float4*)&As[kk][ty * 4];
            float4 bv4 = *(const float4*)&Bs[kk][tx * 4];
            float a[4] = {av.x, av.y, av.z, av.w};
            float b[4] = {bv4.x, bv4.y, bv4.z, bv4.w};
            #pragma unroll
            for (int i = 0; i < 4; ++i)
                #pragma unroll
                for (int j = 0; j < 4; ++j)
                    acc[i][j] = fmaf(a[i], b[j], acc[i][j]);
        }
    }

    float bj[4];
    #pragma unroll
    for (int j = 0; j < 4; ++j) bj[j] = bo[n0 + tx * 4 + j];
    #pragma unroll
    for (int i = 0; i < 4; ++i) {
        float4 c;
        c.x = acc[i][0] + bj[0];
        c.y = acc[i][1] + bj[1];
        c.z = acc[i][2] + bj[2];
        c.w = acc[i][3] + bj[3];
        *(float4*)&out[(size_t)(m0 + ty * 4 + i) * DM + n0 + tx * 4] = c;
    }
}

extern "C" void kernel_launch(void* const* d_in, const int* in_sizes, int n_in,
                              void* d_out, int out_size, void* d_ws, size_t ws_size,
                              hipStream_t stream) {
    const float* x  = (const float*)d_in[0];
    // d_in[1] = mask: exactly causal, reconstructed analytically — unused.
    const float* Wq = (const float*)d_in[2];
    const float* bq = (const float*)d_in[3];
    const float* Wk = (const float*)d_in[4];
    const float* bk = (const float*)d_in[5];
    const float* Wv = (const float*)d_in[6];
    const float* bv = (const float*)d_in[7];
    const float* Wo = (const float*)d_in[8];
    const float* bo = (const float*)d_in[9];
    float* out = (float*)d_out;

    const size_t qkv_elems = (size_t)4 * NH * S_LEN * HD;   // 4,194,304
    float* Q   = (float*)d_ws;
    float* K   = Q + qkv_elems;
    float* V   = K + qkv_elems;
    float* Att = V + qkv_elems;

    const int M = 4 * S_LEN;   // 8192
    qkv_proj<<<dim3(M / 64, 24), 256, 0, stream>>>(x, Wq, bq, Wk, bk, Wv, bv, Q, K, V);
    attn<<<dim3(S_LEN / 64, 4 * NH), 256, 0, stream>>>(Q, K, V, Att);
    out_proj<<<dim3(M / 64, DM / 64), 256, 0, stream>>>(Att, Wo, bo, out);
}

// Round 2
// 765.846 us; speedup vs baseline: 1.6750x; 1.6750x over previous
//
#include <hip/hip_runtime.h>

#define S_LEN 2048
#define DM    512
#define NH    8
#define HD    64

typedef unsigned short u16;
typedef unsigned int   u32;
typedef __bf16 bf16_t;
typedef bf16_t bf16x8 __attribute__((ext_vector_type(8)));
typedef float  f32x4  __attribute__((ext_vector_type(4)));

// round-to-nearest-even fp32 -> bf16
__device__ __forceinline__ u16 f2bf(float f) {
    u32 u = __float_as_uint(f);
    u += 0x7FFFu + ((u >> 16) & 1u);
    return (u16)(u >> 16);
}

__device__ __forceinline__ float qmax16(float v) {
    v = fmaxf(v, __shfl_xor(v, 1));
    v = fmaxf(v, __shfl_xor(v, 2));
    v = fmaxf(v, __shfl_xor(v, 4));
    v = fmaxf(v, __shfl_xor(v, 8));
    return v;
}
__device__ __forceinline__ float qsum16(float v) {
    v += __shfl_xor(v, 1);
    v += __shfl_xor(v, 2);
    v += __shfl_xor(v, 4);
    v += __shfl_xor(v, 8);
    return v;
}

// ============================================================
// fp32 -> bf16 conversion pre-pass. y selects source.
// ============================================================
__global__ __launch_bounds__(256) void cvt_bf16(
    const float* __restrict__ x,
    const float* __restrict__ wq, const float* __restrict__ wk,
    const float* __restrict__ wv, const float* __restrict__ wo,
    u16* __restrict__ xb, u16* __restrict__ wqb, u16* __restrict__ wkb,
    u16* __restrict__ wvb, u16* __restrict__ wob)
{
    const int y = blockIdx.y;
    const float* src; u16* dst; int n;
    if (y == 0)      { src = x;  dst = xb;  n = 4 * S_LEN * DM; }
    else if (y == 1) { src = wq; dst = wqb; n = DM * DM; }
    else if (y == 2) { src = wk; dst = wkb; n = DM * DM; }
    else if (y == 3) { src = wv; dst = wvb; n = DM * DM; }
    else             { src = wo; dst = wob; n = DM * DM; }
    int idx = (blockIdx.x * 256 + threadIdx.x) * 8;
    if (idx >= n) return;
    float4 f0 = *(const float4*)(src + idx);
    float4 f1 = *(const float4*)(src + idx + 4);
    u32 p0 = (u32)f2bf(f0.x) | ((u32)f2bf(f0.y) << 16);
    u32 p1 = (u32)f2bf(f0.z) | ((u32)f2bf(f0.w) << 16);
    u32 p2 = (u32)f2bf(f1.x) | ((u32)f2bf(f1.y) << 16);
    u32 p3 = (u32)f2bf(f1.z) | ((u32)f2bf(f1.w) << 16);
    *(uint4*)(dst + idx) = make_uint4(p0, p1, p2, p3);
}

// ============================================================
// Fused QKV MFMA GEMM: C = X @ W^T + b, 128x128 tile, BK=32.
// 4 waves in 2x2, each wave 64x64 via 4x4 grid of 16x16x32 mfma.
// LDS layout: k-blocked chunks of 8 bf16, XOR-swizzled:
//   chunk(row,kq) = row*4 + (kq ^ ((row>>1)&3))   (<=2-way conflicts = free)
// Output written bf16 in [B, H, S, HD] layout, bias fused.
// ============================================================
__global__ __launch_bounds__(256) void qkv_gemm(
    const u16* __restrict__ xb,
    const u16* __restrict__ Wqb, const u16* __restrict__ Wkb, const u16* __restrict__ Wvb,
    const float* __restrict__ bq, const float* __restrict__ bk, const float* __restrict__ bv,
    u16* __restrict__ Qb, u16* __restrict__ Kb, u16* __restrict__ Vb)
{
    __shared__ u16 Als[4096];   // 128 rows x 32 k (bf16), swizzled chunks
    __shared__ u16 Bls[4096];

    const int t = threadIdx.x;
    const int lane = t & 63, w = t >> 6;
    const int ln = lane & 15, quad = lane >> 4;
    const int wm = w >> 1, wn = w & 1;
    const int m0 = blockIdx.x * 128;
    const int mat = blockIdx.y >> 2;          // 0=Q 1=K 2=V
    const int n0 = (blockIdx.y & 3) * 128;

    const u16* __restrict__ Wb    = (mat == 0) ? Wqb : (mat == 1) ? Wkb : Wvb;
    const float* __restrict__ bias = (mat == 0) ? bq : (mat == 1) ? bk : bv;
    u16* __restrict__ outp         = (mat == 0) ? Qb : (mat == 1) ? Kb : Vb;

    const int c0 = t, c1 = t + 256;
    const int r0 = c0 >> 2, kq0 = c0 & 3, ch0 = r0 * 4 + (kq0 ^ ((r0 >> 1) & 3));
    const int r1 = c1 >> 2, kq1 = c1 & 3, ch1 = r1 * 4 + (kq1 ^ ((r1 >> 1) & 3));

    f32x4 acc[4][4] = {};
    for (int k0 = 0; k0 < DM; k0 += 32) {
        uint4 a0 = *(const uint4*)(xb + (size_t)(m0 + r0) * DM + k0 + kq0 * 8);
        uint4 a1 = *(const uint4*)(xb + (size_t)(m0 + r1) * DM + k0 + kq1 * 8);
        uint4 b0 = *(const uint4*)(Wb + (size_t)(n0 + r0) * DM + k0 + kq0 * 8);
        uint4 b1 = *(const uint4*)(Wb + (size_t)(n0 + r1) * DM + k0 + kq1 * 8);
        __syncthreads();
        *(uint4*)(Als + ch0 * 8) = a0;
        *(uint4*)(Als + ch1 * 8) = a1;
        *(uint4*)(Bls + ch0 * 8) = b0;
        *(uint4*)(Bls + ch1 * 8) = b1;
        __syncthreads();
        bf16x8 af[4], bf8[4];
        #pragma unroll
        for (int i = 0; i < 4; ++i) {
            int row = wm * 64 + i * 16 + ln;
            af[i] = *(const bf16x8*)(Als + (row * 4 + (quad ^ ((row >> 1) & 3))) * 8);
        }
        #pragma unroll
        for (int j = 0; j < 4; ++j) {
            int row = wn * 64 + j * 16 + ln;
            bf8[j] = *(const bf16x8*)(Bls + (row * 4 + (quad ^ ((row >> 1) & 3))) * 8);
        }
        #pragma unroll
        for (int i = 0; i < 4; ++i)
            #pragma unroll
            for (int j = 0; j < 4; ++j)
                acc[i][j] = __builtin_amdgcn_mfma_f32_16x16x32_bf16(af[i], bf8[j], acc[i][j], 0, 0, 0);
    }

    // epilogue: C/D layout col=lane&15, row=quad*4+reg  [verified m89/m91]
    #pragma unroll
    for (int j = 0; j < 4; ++j) {
        int colg = n0 + wn * 64 + j * 16 + ln;
        float bj = bias[colg];
        int h = colg >> 6, d = colg & 63;
        #pragma unroll
        for (int i = 0; i < 4; ++i) {
            int mbase = m0 + wm * 64 + i * 16 + quad * 4;
            #pragma unroll
            for (int r = 0; r < 4; ++r) {
                int m = mbase + r;
                int bb = m >> 11, s = m & 2047;
                outp[(((size_t)bb * NH + h) * S_LEN + s) * HD + d] = f2bf(acc[i][j][r] + bj);
            }
        }
    }
}

// ============================================================
// Flash attention, bf16 MFMA, causal. grid = (16, B*H).
// Block: 128 q-rows (4 waves x 32), K/V tiles of 64.
// Softmax state in registers (quad shfl reductions).
// P: C-layout -> LDS (bf16) -> A-layout reload (verified m120 pattern).
// LDS tiles XOR-swizzled: chunk(row,kq)=row*8+(kq^(row&7)).
// ============================================================
__global__ __launch_bounds__(256) void attn_mfma(
    const u16* __restrict__ Qb, const u16* __restrict__ Kb, const u16* __restrict__ Vb,
    u16* __restrict__ Attb)
{
    __shared__ u16 Qls[8192];   // 128 x 64
    __shared__ u16 Kls[4096];   // 64 keys x 64 d
    __shared__ u16 Vt[4096];    // 64 d x 64 keys (transposed)
    __shared__ u16 Ps[8192];    // 128 q x 64 keys

    const int t = threadIdx.x;
    const int lane = t & 63, w = t >> 6;
    const int ln = lane & 15, quad = lane >> 4;
    const int qt = blockIdx.x, bh = blockIdx.y;
    const int q_base = qt * 128;
    const size_t base = (size_t)bh * S_LEN * HD;

    // stage Q tile (128x64 bf16)
    #pragma unroll
    for (int cc = 0; cc < 4; ++cc) {
        int c = t + cc * 256;
        int row = c >> 3, kq = c & 7;
        uint4 v = *(const uint4*)(Qb + base + (size_t)(q_base + row) * HD + kq * 8);
        *(uint4*)(Qls + (row * 8 + (kq ^ (row & 7))) * 8) = v;
    }
    __syncthreads();

    // preload Q A-frags (held in regs for whole kernel)
    bf16x8 aq[2][2];
    #pragma unroll
    for (int i = 0; i < 2; ++i)
        #pragma unroll
        for (int ks = 0; ks < 2; ++ks) {
            int row = w * 32 + i * 16 + ln;
            int kqg = ks * 4 + quad;
            aq[i][ks] = *(const bf16x8*)(Qls + (row * 8 + (kqg ^ (row & 7))) * 8);
        }

    float m_st[2][4], l_st[2][4];
    f32x4 o[2][4] = {};
    #pragma unroll
    for (int i = 0; i < 2; ++i)
        #pragma unroll
        for (int r = 0; r < 4; ++r) { m_st[i][r] = -1e30f; l_st[i][r] = 0.f; }

    const int ktmax = (q_base + 127) >> 6;
    const int qrow0 = q_base + w * 32;

    for (int kt = 0; kt <= ktmax; ++kt) {
        // ---- stage K tile ----
        #pragma unroll
        for (int cc = 0; cc < 2; ++cc) {
            int c = t + cc * 256;
            int row = c >> 3, kq = c & 7;
            uint4 v = *(const uint4*)(Kb + base + (size_t)(kt * 64 + row) * HD + kq * 8);
            *(uint4*)(Kls + (row * 8 + (kq ^ (row & 7))) * 8) = v;
        }
        // ---- stage V transposed (lane-rotated scalar writes: conflict-free) ----
        #pragma unroll
        for (int cc = 0; cc < 2; ++cc) {
            int c = t + cc * 256;
            int kv = c >> 3, d0 = (c & 7) * 8;
            uint4 vv = *(const uint4*)(Vb + base + (size_t)(kt * 64 + kv) * HD + d0);
            u16 ve[8];
            *(uint4*)ve = vv;
            int kvq = kv >> 3, kvl = kv & 7;
            #pragma unroll
            for (int ii = 0; ii < 8; ++ii) {
                int i = (ii + (t & 7)) & 7;
                int d = d0 + i;
                Vt[(d * 8 + (kvq ^ (d & 7))) * 8 + kvl] = ve[i];
            }
        }
        __syncthreads();

        // ---- S = Q K^T ----
        f32x4 s[2][4] = {};
        #pragma unroll
        for (int ks = 0; ks < 2; ++ks)
            #pragma unroll
            for (int j = 0; j < 4; ++j) {
                int row = j * 16 + ln;
                int kqg = ks * 4 + quad;
                bf16x8 bk8 = *(const bf16x8*)(Kls + (row * 8 + (kqg ^ (row & 7))) * 8);
                #pragma unroll
                for (int i = 0; i < 2; ++i)
                    s[i][j] = __builtin_amdgcn_mfma_f32_16x16x32_bf16(aq[i][ks], bk8, s[i][j], 0, 0, 0);
            }

        // ---- scale + causal mask ----
        bool need_mask = (kt * 64 + 63) > qrow0;
        #pragma unroll
        for (int i = 0; i < 2; ++i)
            #pragma unroll
            for (int j = 0; j < 4; ++j)
                #pragma unroll
                for (int r = 0; r < 4; ++r) {
                    float sv = s[i][j][r] * 0.125f;
                    if (need_mask) {
                        int qg = qrow0 + i * 16 + quad * 4 + r;
                        int kg = kt * 64 + j * 16 + ln;
                        if (kg > qg) sv = -1e30f;
                    }
                    s[i][j][r] = sv;
                }

        // ---- online softmax (registers + quad shuffles only) ----
        float alpha[2][4];
        #pragma unroll
        for (int i = 0; i < 2; ++i)
            #pragma unroll
            for (int r = 0; r < 4; ++r) {
                float mx = fmaxf(fmaxf(s[i][0][r], s[i][1][r]), fmaxf(s[i][2][r], s[i][3][r]));
                mx = qmax16(mx);
                float mnew = fmaxf(m_st[i][r], mx);
                float al = __expf(m_st[i][r] - mnew);
                m_st[i][r] = mnew;
                float rs = 0.f;
                #pragma unroll
                for (int j = 0; j < 4; ++j) {
                    float p = __expf(s[i][j][r] - mnew);
                    s[i][j][r] = p;
                    rs += p;
                }
                rs = qsum16(rs);
                l_st[i][r] = l_st[i][r] * al + rs;
                alpha[i][r] = al;
            }
        #pragma unroll
        for (int i = 0; i < 2; ++i)
            #pragma unroll
            for (int j = 0; j < 4; ++j)
                #pragma unroll
                for (int r = 0; r < 4; ++r)
                    o[i][j][r] *= alpha[i][r];

        // ---- P (C-layout) -> LDS bf16 ----
        #pragma unroll
        for (int i = 0; i < 2; ++i)
            #pragma unroll
            for (int j = 0; j < 4; ++j) {
                int key = j * 16 + ln;
                int kq = key >> 3, kl = key & 7;
                #pragma unroll
                for (int r = 0; r < 4; ++r) {
                    int qloc = w * 32 + i * 16 + quad * 4 + r;
                    Ps[(qloc * 8 + (kq ^ (qloc & 7))) * 8 + kl] = f2bf(s[i][j][r]);
                }
            }

        // ---- O += P @ V ----
        #pragma unroll
        for (int ks = 0; ks < 2; ++ks) {
            int kqg = ks * 4 + quad;
            bf16x8 pa[2];
            #pragma unroll
            for (int i = 0; i < 2; ++i) {
                int row = w * 32 + i * 16 + ln;
                pa[i] = *(const bf16x8*)(Ps + (row * 8 + (kqg ^ (row & 7))) * 8);
            }
            #pragma unroll
            for (int j = 0; j < 4; ++j) {
                int rowd = j * 16 + ln;
                bf16x8 vb8 = *(const bf16x8*)(Vt + (rowd * 8 + (kqg ^ (rowd & 7))) * 8);
                #pragma unroll
                for (int i = 0; i < 2; ++i)
                    o[i][j] = __builtin_amdgcn_mfma_f32_16x16x32_bf16(pa[i], vb8, o[i][j], 0, 0, 0);
            }
        }
        __syncthreads();   // protect Kls/Vt for next iteration
    }

    // ---- epilogue: normalize, write attended bf16 [B*S, DM] ----
    const int bb = bh >> 3, h = bh & 7;
    #pragma unroll
    for (int i = 0; i < 2; ++i)
        #pragma unroll
        for (int r = 0; r < 4; ++r) {
            int qg = qrow0 + i * 16 + quad * 4 + r;
            float inv = 1.f / l_st[i][r];
            #pragma unroll
            for (int j = 0; j < 4; ++j) {
                int d = j * 16 + ln;
                Attb[((size_t)(bb * S_LEN + qg)) * DM + h * HD + d] = f2bf(o[i][j][r] * inv);
            }
        }
}

// ============================================================
// Output projection: out = A @ Wo^T + bo  (fp32 out), same tiling.
// ============================================================
__global__ __launch_bounds__(256) void out_gemm(
    const u16* __restrict__ Ab, const u16* __restrict__ Wob,
    const float* __restrict__ bo, float* __restrict__ out)
{
    __shared__ u16 Als[4096];
    __shared__ u16 Bls[4096];

    const int t = threadIdx.x;
    const int lane = t & 63, w = t >> 6;
    const int ln = lane & 15, quad = lane >> 4;
    const int wm = w >> 1, wn = w & 1;
    const int m0 = blockIdx.x * 128;
    const int n0 = blockIdx.y * 128;

    const int c0 = t, c1 = t + 256;
    const int r0 = c0 >> 2, kq0 = c0 & 3, ch0 = r0 * 4 + (kq0 ^ ((r0 >> 1) & 3));
    const int r1 = c1 >> 2, kq1 = c1 & 3, ch1 = r1 * 4 + (kq1 ^ ((r1 >> 1) & 3));

    f32x4 acc[4][4] = {};
    for (int k0 = 0; k0 < DM; k0 += 32) {
        uint4 a0 = *(const uint4*)(Ab + (size_t)(m0 + r0) * DM + k0 + kq0 * 8);
        uint4 a1 = *(const uint4*)(Ab + (size_t)(m0 + r1) * DM + k0 + kq1 * 8);
        uint4 b0 = *(const uint4*)(Wob + (size_t)(n0 + r0) * DM + k0 + kq0 * 8);
        uint4 b1 = *(const uint4*)(Wob + (size_t)(n0 + r1) * DM + k0 + kq1 * 8);
        __syncthreads();
        *(uint4*)(Als + ch0 * 8) = a0;
        *(uint4*)(Als + ch1 * 8) = a1;
        *(uint4*)(Bls + ch0 * 8) = b0;
        *(uint4*)(Bls + ch1 * 8) = b1;
        __syncthreads();
        bf16x8 af[4], bf8[4];
        #pragma unroll
        for (int i = 0; i < 4; ++i) {
            int row = wm * 64 + i * 16 + ln;
            af[i] = *(const bf16x8*)(Als + (row * 4 + (quad ^ ((row >> 1) & 3))) * 8);
        }
        #pragma unroll
        for (int j = 0; j < 4; ++j) {
            int row = wn * 64 + j * 16 + ln;
            bf8[j] = *(const bf16x8*)(Bls + (row * 4 + (quad ^ ((row >> 1) & 3))) * 8);
        }
        #pragma unroll
        for (int i = 0; i < 4; ++i)
            #pragma unroll
            for (int j = 0; j < 4; ++j)
                acc[i][j] = __builtin_amdgcn_mfma_f32_16x16x32_bf16(af[i], bf8[j], acc[i][j], 0, 0, 0);
    }

    #pragma unroll
    for (int j = 0; j < 4; ++j) {
        int colg = n0 + wn * 64 + j * 16 + ln;
        float bj = bo[colg];
        #pragma unroll
        for (int i = 0; i < 4; ++i) {
            int mbase = m0 + wm * 64 + i * 16 + quad * 4;
            #pragma unroll
            for (int r = 0; r < 4; ++r) {
                int m = mbase + r;
                out[(size_t)m * DM + colg] = acc[i][j][r] + bj;
            }
        }
    }
}

extern "C" void kernel_launch(void* const* d_in, const int* in_sizes, int n_in,
                              void* d_out, int out_size, void* d_ws, size_t ws_size,
                              hipStream_t stream) {
    const float* x  = (const float*)d_in[0];
    // d_in[1] = mask: exactly causal, handled analytically — unused.
    const float* Wq = (const float*)d_in[2];
    const float* bq = (const float*)d_in[3];
    const float* Wk = (const float*)d_in[4];
    const float* bk = (const float*)d_in[5];
    const float* Wv = (const float*)d_in[6];
    const float* bv = (const float*)d_in[7];
    const float* Wo = (const float*)d_in[8];
    const float* bo = (const float*)d_in[9];
    float* out = (float*)d_out;

    u16* ws = (u16*)d_ws;
    const size_t NX = (size_t)4 * S_LEN * DM;   // 4194304
    const size_t NW = (size_t)DM * DM;          // 262144
    u16* xb   = ws;
    u16* wqb  = xb + NX;
    u16* wkb  = wqb + NW;
    u16* wvb  = wkb + NW;
    u16* wob  = wvb + NW;
    u16* Qb   = wob + NW;
    u16* Kb   = Qb + NX;
    u16* Vb   = Kb + NX;
    u16* Attb = Vb + NX;
    // total ws use: (5*NX + 4*NW)*2 = 44 MB

    cvt_bf16<<<dim3(2048, 5), 256, 0, stream>>>(x, Wq, Wk, Wv, Wo, xb, wqb, wkb, wvb, wob);
    qkv_gemm<<<dim3(64, 12), 256, 0, stream>>>(xb, wqb, wkb, wvb, bq, bk, bv, Qb, Kb, Vb);
    attn_mfma<<<dim3(16, 32), 256, 0, stream>>>(Qb, Kb, Vb, Attb);
    out_gemm<<<dim3(64, 4), 256, 0, stream>>>(Attb, wob, bo, out);
}